// Round 1
// baseline (235.379 us; speedup 1.0000x reference)
//
#include <hip/hip_runtime.h>
#include <hip/hip_bf16.h>
#include <stdint.h>

typedef unsigned short u16;
typedef __attribute__((ext_vector_type(8))) __bf16 bf16x8;
typedef __attribute__((ext_vector_type(4))) float f32x4;

#define AS1(p) ((const __attribute__((address_space(1))) void*)(p))
#define AS3(p) ((__attribute__((address_space(3))) void*)(p))

__device__ __forceinline__ u16 f2bf(float f) {
  union { float f; uint32_t u; } c; c.f = f;
  uint32_t u = c.u;
  u += 0x7fffu + ((u >> 16) & 1u);   // RTNE
  return (u16)(u >> 16);
}

// ---------------- cast fp32 -> bf16 (vectorized, grid-stride) ----------------
__global__ __launch_bounds__(256) void cast_f32_bf16(const float4* __restrict__ in,
                                                     ushort4* __restrict__ out, int n4) {
  int i = blockIdx.x * blockDim.x + threadIdx.x;
  int stride = gridDim.x * blockDim.x;
  for (; i < n4; i += stride) {
    float4 v = in[i];
    ushort4 o;
    o.x = f2bf(v.x); o.y = f2bf(v.y); o.z = f2bf(v.z); o.w = f2bf(v.w);
    out[i] = o;
  }
}

// ---------------- NT GEMM: C[M][N] = scale * (A[M][K] . B[N][K]^T), bf16 ----------------
// 128x128 tile, BK=32, 4 waves (each 64x64 = 4x4 frags of 16x16x32), global_load_lds staging.
__global__ __launch_bounds__(256) void gemm_nt_bf16(const u16* __restrict__ A,
                                                    const u16* __restrict__ B,
                                                    u16* __restrict__ C,
                                                    int M, int N, int K, float scale) {
  __shared__ u16 As[128 * 32];
  __shared__ u16 Bs[128 * 32];
  const int tiles_n = N >> 7;
  int bm = blockIdx.x / tiles_n;
  int bn = blockIdx.x % tiles_n;
  int tid = threadIdx.x;
  int w = tid >> 6, l = tid & 63;
  int wr = w >> 1, wc = w & 1;
  int lr = l & 15, lg = l >> 4;

  f32x4 acc[4][4];
#pragma unroll
  for (int i = 0; i < 4; ++i)
#pragma unroll
    for (int j = 0; j < 4; ++j) acc[i][j] = (f32x4){0.f, 0.f, 0.f, 0.f};

  for (int k0 = 0; k0 < K; k0 += 32) {
#pragma unroll
    for (int t = 0; t < 2; ++t) {
      int seg = w * 2 + t;  // 8 segments of 1024B per tile; wave-uniform LDS base
      const u16* ga = A + (size_t)(bm * 128 + seg * 16 + (l >> 2)) * K + k0 + (l & 3) * 8;
      __builtin_amdgcn_global_load_lds(AS1(ga), AS3(As + seg * 512), 16, 0, 0);
      const u16* gb = B + (size_t)(bn * 128 + seg * 16 + (l >> 2)) * K + k0 + (l & 3) * 8;
      __builtin_amdgcn_global_load_lds(AS1(gb), AS3(Bs + seg * 512), 16, 0, 0);
    }
    __syncthreads();
    bf16x8 af[4], bb[4];
#pragma unroll
    for (int i = 0; i < 4; ++i)
      af[i] = *(const bf16x8*)(As + (wr * 64 + i * 16 + lr) * 32 + lg * 8);
#pragma unroll
    for (int j = 0; j < 4; ++j)
      bb[j] = *(const bf16x8*)(Bs + (wc * 64 + j * 16 + lr) * 32 + lg * 8);
#pragma unroll
    for (int i = 0; i < 4; ++i)
#pragma unroll
      for (int j = 0; j < 4; ++j)
        acc[i][j] = __builtin_amdgcn_mfma_f32_16x16x32_bf16(af[i], bb[j], acc[i][j], 0, 0, 0);
    __syncthreads();
  }
  // epilogue: C/D layout col=lane&15, row=(lane>>4)*4+reg
#pragma unroll
  for (int i = 0; i < 4; ++i)
#pragma unroll
    for (int j = 0; j < 4; ++j)
#pragma unroll
      for (int r = 0; r < 4; ++r) {
        int row = bm * 128 + wr * 64 + i * 16 + lg * 4 + r;
        int col = bn * 128 + wc * 64 + j * 16 + lr;
        C[(size_t)row * N + col] = f2bf(acc[i][j][r] * scale);
      }
}

// ---------------- flash attention ----------------
// grid = (S/64) * B * H blocks; 256 threads (4 waves), each wave owns 16 q-rows.
// Q pre-scaled by HD^-0.5. LDS XOR-swizzled: byte = row*128 + (cb ^ ((row&7)<<4)).
#define SQ 2048

__global__ __launch_bounds__(256) void attn_kernel(const u16* __restrict__ Q,
                                                   const u16* __restrict__ KV,
                                                   float* __restrict__ O) {
  __shared__ u16 Qs[64 * 64];
  __shared__ u16 Ks[64 * 64];
  __shared__ u16 Vt[64 * 64];  // V transposed: [d][j]
  __shared__ u16 Ps[64 * 64];  // P, per-wave 16-row slices

  const int nqt = SQ / 64;
  int qt = blockIdx.x % nqt;
  int bh = blockIdx.x / nqt;
  int b = bh >> 4, h = bh & 15;
  int tid = threadIdx.x, w = tid >> 6, l = tid & 63;
  int lr = l & 15, lg = l >> 4;

  const u16* qbase = Q + (size_t)b * SQ * 1024 + (size_t)h * 64;
  const u16* kbase = KV + (size_t)b * SQ * 2048 + (size_t)h * 64;
  const u16* vbase = kbase + 1024;

  int i0 = qt * 64;
  // stage Q once (64 rows x 64 cols bf16)
#pragma unroll
  for (int t = 0; t < 2; ++t) {
    int c = tid + t * 256;
    int row = c >> 3, d0 = (c & 7) * 8;
    uint4 v = *(const uint4*)(qbase + (size_t)(i0 + row) * 1024 + d0);
    *(uint4*)((char*)Qs + row * 128 + ((d0 * 2) ^ ((row & 7) << 4))) = v;
  }

  float m_i[4] = {-1e30f, -1e30f, -1e30f, -1e30f};
  float l_i[4] = {0.f, 0.f, 0.f, 0.f};
  f32x4 acc[4];
#pragma unroll
  for (int nf = 0; nf < 4; ++nf) acc[nf] = (f32x4){0.f, 0.f, 0.f, 0.f};

  for (int j0 = 0; j0 < SQ; j0 += 64) {
    __syncthreads();  // prev-iter reads done before overwriting K/V (also covers Q stage)
    // stage K (row-major [j][c])
#pragma unroll
    for (int t = 0; t < 2; ++t) {
      int c = tid + t * 256;
      int row = c >> 3, d0 = (c & 7) * 8;
      uint4 v = *(const uint4*)(kbase + (size_t)(j0 + row) * 2048 + d0);
      *(uint4*)((char*)Ks + row * 128 + ((d0 * 2) ^ ((row & 7) << 4))) = v;
    }
    // stage V transposed into Vt[d][j]
#pragma unroll
    for (int t = 0; t < 2; ++t) {
      int c = tid + t * 256;
      int j = c >> 3, d0 = (c & 7) * 8;
      uint4 v = *(const uint4*)(vbase + (size_t)(j0 + j) * 2048 + d0);
      const u16* pv = (const u16*)&v;
#pragma unroll
      for (int e = 0; e < 8; ++e) {
        int d = d0 + e;
        *(u16*)((char*)Vt + d * 128 + ((j * 2) ^ ((d & 7) << 4))) = pv[e];
      }
    }
    __syncthreads();

    // S = Q.K^T : wave w computes rows w*16..w*16+15 x all 64 cols
    bf16x8 aq[2];
#pragma unroll
    for (int kk = 0; kk < 2; ++kk) {
      int row = w * 16 + lr;
      aq[kk] = *(const bf16x8*)((const char*)Qs + row * 128 + ((kk * 64 + lg * 16) ^ ((row & 7) << 4)));
    }
    f32x4 s[4];
#pragma unroll
    for (int nf = 0; nf < 4; ++nf) {
      s[nf] = (f32x4){0.f, 0.f, 0.f, 0.f};
#pragma unroll
      for (int kk = 0; kk < 2; ++kk) {
        int row = nf * 16 + lr;
        bf16x8 bk = *(const bf16x8*)((const char*)Ks + row * 128 + ((kk * 64 + lg * 16) ^ ((row & 7) << 4)));
        s[nf] = __builtin_amdgcn_mfma_f32_16x16x32_bf16(aq[kk], bk, s[nf], 0, 0, 0);
      }
    }
    // online softmax: lane holds rows lg*4+r (local), col nf*16+lr
    float p[4][4];
#pragma unroll
    for (int r = 0; r < 4; ++r) {
      float mx = fmaxf(fmaxf(s[0][r], s[1][r]), fmaxf(s[2][r], s[3][r]));
      mx = fmaxf(mx, __shfl_xor(mx, 1));
      mx = fmaxf(mx, __shfl_xor(mx, 2));
      mx = fmaxf(mx, __shfl_xor(mx, 4));
      mx = fmaxf(mx, __shfl_xor(mx, 8));
      float mn = fmaxf(m_i[r], mx);
      float esc = __expf(m_i[r] - mn);
      m_i[r] = mn;
      float su = 0.f;
#pragma unroll
      for (int nf = 0; nf < 4; ++nf) { p[nf][r] = __expf(s[nf][r] - mn); su += p[nf][r]; }
      su += __shfl_xor(su, 1);
      su += __shfl_xor(su, 2);
      su += __shfl_xor(su, 4);
      su += __shfl_xor(su, 8);
      l_i[r] = l_i[r] * esc + su;
#pragma unroll
      for (int nf = 0; nf < 4; ++nf) acc[nf][r] *= esc;
    }
    // P -> LDS (bf16), wave-local region rows w*16..
#pragma unroll
    for (int nf = 0; nf < 4; ++nf)
#pragma unroll
      for (int r = 0; r < 4; ++r) {
        int row = w * 16 + lg * 4 + r;
        int cb2 = (nf * 16 + lr) * 2;
        *(u16*)((char*)Ps + row * 128 + (cb2 ^ ((row & 7) << 4))) = f2bf(p[nf][r]);
      }
    // O += P.V  (A = P rows, B = Vt rows = d-cols, contiguous in j)
    bf16x8 ap[2];
#pragma unroll
    for (int kk = 0; kk < 2; ++kk) {
      int row = w * 16 + lr;
      ap[kk] = *(const bf16x8*)((const char*)Ps + row * 128 + ((kk * 64 + lg * 16) ^ ((row & 7) << 4)));
    }
#pragma unroll
    for (int nf = 0; nf < 4; ++nf)
#pragma unroll
      for (int kk = 0; kk < 2; ++kk) {
        int row = nf * 16 + lr;
        bf16x8 bv = *(const bf16x8*)((const char*)Vt + row * 128 + ((kk * 64 + lg * 16) ^ ((row & 7) << 4)));
        acc[nf] = __builtin_amdgcn_mfma_f32_16x16x32_bf16(ap[kk], bv, acc[nf], 0, 0, 0);
      }
  }
  // epilogue: out[b, i, h*64 + d] = acc / l
#pragma unroll
  for (int nf = 0; nf < 4; ++nf)
#pragma unroll
    for (int r = 0; r < 4; ++r) {
      int row = i0 + w * 16 + lg * 4 + r;
      int col = h * 64 + nf * 16 + lr;
      O[((size_t)b * SQ + row) * 1024 + col] = acc[nf][r] / l_i[r];
    }
}

extern "C" void kernel_launch(void* const* d_in, const int* in_sizes, int n_in,
                              void* d_out, int out_size, void* d_ws, size_t ws_size,
                              hipStream_t stream) {
  (void)in_sizes; (void)n_in; (void)out_size; (void)ws_size;
  const float* x   = (const float*)d_in[0];
  const float* ctx = (const float*)d_in[1];
  const float* Wq  = (const float*)d_in[2];
  const float* Wkv = (const float*)d_in[3];
  float* out = (float*)d_out;
  char* ws = (char*)d_ws;

  // workspace layout (46 MB total)
  u16* xb  = (u16*)(ws);                       // x bf16   [4096][1024]  8 MB
  u16* cb  = (u16*)(ws + (8ull  << 20));       // ctx bf16 [4096][1024]  8 MB
  u16* wqb = (u16*)(ws + (16ull << 20));       // Wq bf16  [1024][1024]  2 MB
  u16* wkb = (u16*)(ws + (18ull << 20));       // Wkv bf16 [2048][1024]  4 MB
  u16* q   = (u16*)(ws + (22ull << 20));       // q bf16   [4096][1024]  8 MB (pre-scaled)
  u16* kv  = (u16*)(ws + (30ull << 20));       // kv bf16  [4096][2048] 16 MB

  auto cast = [&](const float* src, u16* dst, int n) {
    int n4 = n >> 2;
    int blocks = (n4 + 255) / 256;
    if (blocks > 2048) blocks = 2048;
    cast_f32_bf16<<<blocks, 256, 0, stream>>>((const float4*)src, (ushort4*)dst, n4);
  };
  cast(x,   xb,  4096 * 1024);
  cast(ctx, cb,  4096 * 1024);
  cast(Wq,  wqb, 1024 * 1024);
  cast(Wkv, wkb, 2048 * 1024);

  // q = 0.125 * x . Wq^T   (M=4096, N=1024, K=1024)
  gemm_nt_bf16<<<32 * 8, 256, 0, stream>>>(xb, wqb, q, 4096, 1024, 1024, 0.125f);
  // kv = ctx . Wkv^T       (M=4096, N=2048, K=1024)
  gemm_nt_bf16<<<32 * 16, 256, 0, stream>>>(cb, wkb, kv, 4096, 2048, 1024, 1.0f);

  // attention: 32 q-tiles x 32 (b,h)
  attn_kernel<<<32 * 32, 256, 0, stream>>>(q, kv, out);
}

// Round 2
// 137.861 us; speedup vs baseline: 1.7074x; 1.7074x over previous
//
#include <hip/hip_runtime.h>
#include <hip/hip_bf16.h>
#include <stdint.h>

typedef unsigned short u16;
typedef __attribute__((ext_vector_type(8))) __bf16 bf16x8;
typedef __attribute__((ext_vector_type(4))) float f32x4;
typedef __attribute__((ext_vector_type(16))) float f32x16;

#define AS1(p) ((const __attribute__((address_space(1))) void*)(p))
#define AS3(p) ((__attribute__((address_space(3))) void*)(p))

__device__ __forceinline__ u16 f2bf(float f) {
  union { float f; uint32_t u; } c; c.f = f;
  uint32_t u = c.u;
  u += 0x7fffu + ((u >> 16) & 1u);   // RTNE
  return (u16)(u >> 16);
}

// ---------------- cast fp32 -> bf16 (vectorized, grid-stride) ----------------
__global__ __launch_bounds__(256) void cast_f32_bf16(const float4* __restrict__ in,
                                                     ushort4* __restrict__ out, int n4) {
  int i = blockIdx.x * blockDim.x + threadIdx.x;
  int stride = gridDim.x * blockDim.x;
  for (; i < n4; i += stride) {
    float4 v = in[i];
    ushort4 o;
    o.x = f2bf(v.x); o.y = f2bf(v.y); o.z = f2bf(v.z); o.w = f2bf(v.w);
    out[i] = o;
  }
}

// ---------------- NT GEMM: C[M][N] = scale * (A[M][K] . B[N][K]^T), bf16 ----------------
__global__ __launch_bounds__(256) void gemm_nt_bf16(const u16* __restrict__ A,
                                                    const u16* __restrict__ B,
                                                    u16* __restrict__ C,
                                                    int M, int N, int K, float scale) {
  __shared__ u16 As[128 * 32];
  __shared__ u16 Bs[128 * 32];
  const int tiles_n = N >> 7;
  int bm = blockIdx.x / tiles_n;
  int bn = blockIdx.x % tiles_n;
  int tid = threadIdx.x;
  int w = tid >> 6, l = tid & 63;
  int wr = w >> 1, wc = w & 1;
  int lr = l & 15, lg = l >> 4;

  f32x4 acc[4][4];
#pragma unroll
  for (int i = 0; i < 4; ++i)
#pragma unroll
    for (int j = 0; j < 4; ++j) acc[i][j] = (f32x4){0.f, 0.f, 0.f, 0.f};

  for (int k0 = 0; k0 < K; k0 += 32) {
#pragma unroll
    for (int t = 0; t < 2; ++t) {
      int seg = w * 2 + t;
      const u16* ga = A + (size_t)(bm * 128 + seg * 16 + (l >> 2)) * K + k0 + (l & 3) * 8;
      __builtin_amdgcn_global_load_lds(AS1(ga), AS3(As + seg * 512), 16, 0, 0);
      const u16* gb = B + (size_t)(bn * 128 + seg * 16 + (l >> 2)) * K + k0 + (l & 3) * 8;
      __builtin_amdgcn_global_load_lds(AS1(gb), AS3(Bs + seg * 512), 16, 0, 0);
    }
    __syncthreads();
    bf16x8 af[4], bb[4];
#pragma unroll
    for (int i = 0; i < 4; ++i)
      af[i] = *(const bf16x8*)(As + (wr * 64 + i * 16 + lr) * 32 + lg * 8);
#pragma unroll
    for (int j = 0; j < 4; ++j)
      bb[j] = *(const bf16x8*)(Bs + (wc * 64 + j * 16 + lr) * 32 + lg * 8);
#pragma unroll
    for (int i = 0; i < 4; ++i)
#pragma unroll
      for (int j = 0; j < 4; ++j)
        acc[i][j] = __builtin_amdgcn_mfma_f32_16x16x32_bf16(af[i], bb[j], acc[i][j], 0, 0, 0);
    __syncthreads();
  }
#pragma unroll
  for (int i = 0; i < 4; ++i)
#pragma unroll
    for (int j = 0; j < 4; ++j)
#pragma unroll
      for (int r = 0; r < 4; ++r) {
        int row = bm * 128 + wr * 64 + i * 16 + lg * 4 + r;
        int col = bn * 128 + wc * 64 + j * 16 + lr;
        C[(size_t)row * N + col] = f2bf(acc[i][j][r] * scale);
      }
}

// ---------------- flash attention: 8 waves x 32 q-rows, 32x32 swapped QK^T ----------------
// grid = (S/256) * B * H = 256 blocks, 512 threads.
// Lane owns q-row li = l&31 (both hi-halves of the wave hold the two j-halves of that row).
// S^T via mfma(K,Q): reg r of s[jb] -> j = jb*32 + (r&3)+8*(r>>2)+4*hi, col = li.
// O^T via mfma(Vt,P): reg r of acc[db] -> d = db*32 + crow(r,hi), col(q-row) = li.
#define SQ 2048

__global__ __launch_bounds__(512, 1) void attn_kernel(const u16* __restrict__ Q,
                                                      const u16* __restrict__ KV,
                                                      float* __restrict__ O) {
  __shared__ u16 Ks[2 * 64 * 64];  // [buf][j][d], 16B-block bk holds dblk = bk ^ (j&7)
  __shared__ u16 Vt[2 * 64 * 64];  // [buf][d][j], byte = d*128 + ((j*2) ^ (((d^(d>>3))&7)<<4))

  int qt = blockIdx.x & 7;
  int bh = blockIdx.x >> 3;
  int b = bh >> 4, h = bh & 15;
  int tid = threadIdx.x;
  int w = tid >> 6, l = tid & 63;
  int li = l & 31, hi = l >> 5;
  int jr = l >> 3, bk = l & 7;   // K-staging coords (jr 0..7)

  const u16* kbase = KV + (size_t)b * SQ * 2048 + (size_t)h * 64;
  const u16* vbase = kbase + 1024;
  int i0g = qt * 256 + w * 32;
  const u16* qrow = Q + (size_t)(b * SQ + i0g + li) * 1024 + h * 64;

  // Q fragments: qf[kb] = Q[i0g+li][kb*16 + hi*8 + 0..7]
  bf16x8 qf0 = *(const bf16x8*)(qrow + 0  + hi * 8);
  bf16x8 qf1 = *(const bf16x8*)(qrow + 16 + hi * 8);
  bf16x8 qf2 = *(const bf16x8*)(qrow + 32 + hi * 8);
  bf16x8 qf3 = *(const bf16x8*)(qrow + 48 + hi * 8);

  // prologue: stage tile 0 (K via gload_lds with pre-swizzled source; V into regs)
  {
    const u16* gk = kbase + (size_t)(w * 8 + jr) * 2048 + ((bk ^ jr) * 8);
    __builtin_amdgcn_global_load_lds(AS1(gk), AS3(Ks + w * 512), 16, 0, 0);
  }
  uint4 vreg = *(const uint4*)(vbase + (size_t)(tid >> 3) * 2048 + (tid & 7) * 8);

  float m_run = -1e30f, l_run = 0.f;
  f32x16 acc0, acc1;
#pragma unroll
  for (int r = 0; r < 16; ++r) { acc0[r] = 0.f; acc1[r] = 0.f; }

  for (int t = 0; t < SQ / 64; ++t) {
    int cur = t & 1;
    u16* Ksc = Ks + cur * 4096;
    u16* Vtc = Vt + cur * 4096;
    __syncthreads();               // barrier1: K[cur] landed, vreg ready, prev compute done
    // V transpose-store (2-way max: bank block = w ^ e ^ (l&7) varies across d0-groups)
    {
      const u16* pv = (const u16*)&vreg;
      int a = tid & 7, jj = tid >> 3;
#pragma unroll
      for (int e = 0; e < 8; ++e) {
        *(u16*)((char*)Vtc + (a * 8 + e) * 128 + ((jj * 2) ^ ((e ^ a) << 4))) = pv[e];
      }
    }
    __syncthreads();               // barrier2: Vt visible (lgkm only, vmcnt already clean)
    if (t + 1 < SQ / 64) {         // prefetch next tile: in flight across the whole compute
      int nxt = cur ^ 1;
      int j0n = (t + 1) * 64;
      const u16* gk = kbase + (size_t)(j0n + w * 8 + jr) * 2048 + ((bk ^ jr) * 8);
      __builtin_amdgcn_global_load_lds(AS1(gk), AS3(Ks + nxt * 4096 + w * 512), 16, 0, 0);
      vreg = *(const uint4*)(vbase + (size_t)(j0n + (tid >> 3)) * 2048 + (tid & 7) * 8);
    }
    // ---- swapped QK^T
    f32x16 s0, s1;
#pragma unroll
    for (int r = 0; r < 16; ++r) { s0[r] = 0.f; s1[r] = 0.f; }
    int swk = (li & 7) << 4;
#pragma unroll
    for (int kb = 0; kb < 4; ++kb) {
      bf16x8 k0 = *(const bf16x8*)((const char*)Ksc + li * 128        + ((kb * 32 + hi * 16) ^ swk));
      bf16x8 k1 = *(const bf16x8*)((const char*)Ksc + (32 + li) * 128 + ((kb * 32 + hi * 16) ^ swk));
      bf16x8 qq = (kb == 0) ? qf0 : (kb == 1) ? qf1 : (kb == 2) ? qf2 : qf3;
      s0 = __builtin_amdgcn_mfma_f32_32x32x16_bf16(k0, qq, s0, 0, 0, 0);
      s1 = __builtin_amdgcn_mfma_f32_32x32x16_bf16(k1, qq, s1, 0, 0, 0);
    }
    // ---- online softmax, lane-local row
    float pm = s0[0];
#pragma unroll
    for (int r = 1; r < 16; ++r) pm = fmaxf(pm, s0[r]);
#pragma unroll
    for (int r = 0; r < 16; ++r) pm = fmaxf(pm, s1[r]);
    pm = fmaxf(pm, __shfl_xor(pm, 32));
    float mnew = fmaxf(m_run, pm);
    float esc = __expf(m_run - mnew);
    m_run = mnew;
    float p0[16], p1[16];
    float sum = 0.f;
#pragma unroll
    for (int r = 0; r < 16; ++r) { p0[r] = __expf(s0[r] - mnew); sum += p0[r]; }
#pragma unroll
    for (int r = 0; r < 16; ++r) { p1[r] = __expf(s1[r] - mnew); sum += p1[r]; }
    sum += __shfl_xor(sum, 32);
    l_run = l_run * esc + sum;
#pragma unroll
    for (int r = 0; r < 16; ++r) { acc0[r] *= esc; acc1[r] *= esc; }
    // ---- pack P -> bf16 A-frag layout (cvt_pk + permlane32_swap, m214 pattern)
    unsigned pw[16];
#pragma unroll
    for (int i2 = 0; i2 < 8; ++i2) {
      asm("v_cvt_pk_bf16_f32 %0, %1, %2" : "=v"(pw[i2])     : "v"(p0[2 * i2]), "v"(p0[2 * i2 + 1]));
      asm("v_cvt_pk_bf16_f32 %0, %1, %2" : "=v"(pw[8 + i2]) : "v"(p1[2 * i2]), "v"(p1[2 * i2 + 1]));
    }
#pragma unroll
    for (int gB = 0; gB < 2; ++gB) {
      int o = gB * 8;
      asm volatile("v_permlane32_swap_b32 %0, %1" : "+v"(pw[o + 0]), "+v"(pw[o + 2]));
      asm volatile("v_permlane32_swap_b32 %0, %1" : "+v"(pw[o + 1]), "+v"(pw[o + 3]));
      asm volatile("v_permlane32_swap_b32 %0, %1" : "+v"(pw[o + 4]), "+v"(pw[o + 6]));
      asm volatile("v_permlane32_swap_b32 %0, %1" : "+v"(pw[o + 5]), "+v"(pw[o + 7]));
    }
    // ---- PV as O^T: acc[db] += mfma(Vt rows d, P rows i)
#pragma unroll
    for (int kb2 = 0; kb2 < 4; ++kb2) {
      uint4 ufr;
      ufr.x = pw[kb2 * 4 + 0]; ufr.y = pw[kb2 * 4 + 1];
      ufr.z = pw[kb2 * 4 + 2]; ufr.w = pw[kb2 * 4 + 3];
      bf16x8 pa = *(bf16x8*)&ufr;
      int jbyte = kb2 * 32 + hi * 16;
      int d0_ = li, d1_ = 32 + li;
      bf16x8 v0 = *(const bf16x8*)((const char*)Vtc + d0_ * 128 + (jbyte ^ (((d0_ ^ (d0_ >> 3)) & 7) << 4)));
      bf16x8 v1 = *(const bf16x8*)((const char*)Vtc + d1_ * 128 + (jbyte ^ (((d1_ ^ (d1_ >> 3)) & 7) << 4)));
      acc0 = __builtin_amdgcn_mfma_f32_32x32x16_bf16(v0, pa, acc0, 0, 0, 0);
      acc1 = __builtin_amdgcn_mfma_f32_32x32x16_bf16(v1, pa, acc1, 0, 0, 0);
    }
  }
  // ---- epilogue: O[b][i0g+li][h*64 + d], d = db*32 + q + 8g + 4hi
  float inv = 1.f / l_run;
  float* orow = O + ((size_t)(b * SQ + i0g + li) * 1024 + h * 64);
#pragma unroll
  for (int g = 0; g < 4; ++g) {
    f32x4 o0, o1;
#pragma unroll
    for (int q_ = 0; q_ < 4; ++q_) {
      o0[q_] = acc0[g * 4 + q_] * inv;
      o1[q_] = acc1[g * 4 + q_] * inv;
    }
    *(f32x4*)(orow + 8 * g + 4 * hi) = o0;
    *(f32x4*)(orow + 32 + 8 * g + 4 * hi) = o1;
  }
}

extern "C" void kernel_launch(void* const* d_in, const int* in_sizes, int n_in,
                              void* d_out, int out_size, void* d_ws, size_t ws_size,
                              hipStream_t stream) {
  (void)in_sizes; (void)n_in; (void)out_size; (void)ws_size;
  const float* x   = (const float*)d_in[0];
  const float* ctx = (const float*)d_in[1];
  const float* Wq  = (const float*)d_in[2];
  const float* Wkv = (const float*)d_in[3];
  float* out = (float*)d_out;
  char* ws = (char*)d_ws;

  u16* xb  = (u16*)(ws);                       // x bf16   [4096][1024]  8 MB
  u16* cb  = (u16*)(ws + (8ull  << 20));       // ctx bf16 [4096][1024]  8 MB
  u16* wqb = (u16*)(ws + (16ull << 20));       // Wq bf16  [1024][1024]  2 MB
  u16* wkb = (u16*)(ws + (18ull << 20));       // Wkv bf16 [2048][1024]  4 MB
  u16* q   = (u16*)(ws + (22ull << 20));       // q bf16   [4096][1024]  8 MB (pre-scaled)
  u16* kv  = (u16*)(ws + (30ull << 20));       // kv bf16  [4096][2048] 16 MB

  auto cast = [&](const float* src, u16* dst, int n) {
    int n4 = n >> 2;
    int blocks = (n4 + 255) / 256;
    if (blocks > 2048) blocks = 2048;
    cast_f32_bf16<<<blocks, 256, 0, stream>>>((const float4*)src, (ushort4*)dst, n4);
  };
  cast(x,   xb,  4096 * 1024);
  cast(ctx, cb,  4096 * 1024);
  cast(Wq,  wqb, 1024 * 1024);
  cast(Wkv, wkb, 2048 * 1024);

  gemm_nt_bf16<<<32 * 8, 256, 0, stream>>>(xb, wqb, q, 4096, 1024, 1024, 0.125f);
  gemm_nt_bf16<<<32 * 16, 256, 0, stream>>>(cb, wkb, kv, 4096, 2048, 1024, 1.0f);

  attn_kernel<<<256, 512, 0, stream>>>(q, kv, out);
}

// Round 3
// 133.620 us; speedup vs baseline: 1.7616x; 1.0317x over previous
//
#include <hip/hip_runtime.h>
#include <hip/hip_bf16.h>
#include <stdint.h>

typedef unsigned short u16;
typedef __attribute__((ext_vector_type(8))) __bf16 bf16x8;
typedef __attribute__((ext_vector_type(4))) float f32x4;
typedef __attribute__((ext_vector_type(16))) float f32x16;

#define AS1(p) ((const __attribute__((address_space(1))) void*)(p))
#define AS3(p) ((__attribute__((address_space(3))) void*)(p))

__device__ __forceinline__ u16 f2bf(float f) {
  union { float f; uint32_t u; } c; c.f = f;
  uint32_t u = c.u;
  u += 0x7fffu + ((u >> 16) & 1u);   // RTNE
  return (u16)(u >> 16);
}

__device__ __forceinline__ float exp2_fast(float x) {
  float r; asm("v_exp_f32 %0, %1" : "=v"(r) : "v"(x)); return r;
}

// ---------------- cast fp32 -> bf16 (vectorized, grid-stride) ----------------
__global__ __launch_bounds__(256) void cast_f32_bf16(const float4* __restrict__ in,
                                                     ushort4* __restrict__ out, int n4) {
  int i = blockIdx.x * blockDim.x + threadIdx.x;
  int stride = gridDim.x * blockDim.x;
  for (; i < n4; i += stride) {
    float4 v = in[i];
    ushort4 o;
    o.x = f2bf(v.x); o.y = f2bf(v.y); o.z = f2bf(v.z); o.w = f2bf(v.w);
    out[i] = o;
  }
}

// ---------------- NT GEMM: C[M][N] = scale * (A[M][K] . B[N][K]^T), bf16 ----------------
__global__ __launch_bounds__(256) void gemm_nt_bf16(const u16* __restrict__ A,
                                                    const u16* __restrict__ B,
                                                    u16* __restrict__ C,
                                                    int M, int N, int K, float scale) {
  __shared__ u16 As[128 * 32];
  __shared__ u16 Bs[128 * 32];
  const int tiles_n = N >> 7;
  int bm = blockIdx.x / tiles_n;
  int bn = blockIdx.x % tiles_n;
  int tid = threadIdx.x;
  int w = tid >> 6, l = tid & 63;
  int wr = w >> 1, wc = w & 1;
  int lr = l & 15, lg = l >> 4;

  f32x4 acc[4][4];
#pragma unroll
  for (int i = 0; i < 4; ++i)
#pragma unroll
    for (int j = 0; j < 4; ++j) acc[i][j] = (f32x4){0.f, 0.f, 0.f, 0.f};

  for (int k0 = 0; k0 < K; k0 += 32) {
#pragma unroll
    for (int t = 0; t < 2; ++t) {
      int seg = w * 2 + t;
      const u16* ga = A + (size_t)(bm * 128 + seg * 16 + (l >> 2)) * K + k0 + (l & 3) * 8;
      __builtin_amdgcn_global_load_lds(AS1(ga), AS3(As + seg * 512), 16, 0, 0);
      const u16* gb = B + (size_t)(bn * 128 + seg * 16 + (l >> 2)) * K + k0 + (l & 3) * 8;
      __builtin_amdgcn_global_load_lds(AS1(gb), AS3(Bs + seg * 512), 16, 0, 0);
    }
    __syncthreads();
    bf16x8 af[4], bb[4];
#pragma unroll
    for (int i = 0; i < 4; ++i)
      af[i] = *(const bf16x8*)(As + (wr * 64 + i * 16 + lr) * 32 + lg * 8);
#pragma unroll
    for (int j = 0; j < 4; ++j)
      bb[j] = *(const bf16x8*)(Bs + (wc * 64 + j * 16 + lr) * 32 + lg * 8);
#pragma unroll
    for (int i = 0; i < 4; ++i)
#pragma unroll
      for (int j = 0; j < 4; ++j)
        acc[i][j] = __builtin_amdgcn_mfma_f32_16x16x32_bf16(af[i], bb[j], acc[i][j], 0, 0, 0);
    __syncthreads();
  }
#pragma unroll
  for (int i = 0; i < 4; ++i)
#pragma unroll
    for (int j = 0; j < 4; ++j)
#pragma unroll
      for (int r = 0; r < 4; ++r) {
        int row = bm * 128 + wr * 64 + i * 16 + lg * 4 + r;
        int col = bn * 128 + wc * 64 + j * 16 + lr;
        C[(size_t)row * N + col] = f2bf(acc[i][j][r] * scale);
      }
}

// ---------------- flash attention: 4 waves x 32 q-rows, 32x32 swapped QK^T ----------------
// grid = (S/128) * B * H = 512 blocks (2 blocks/CU), 256 threads.
// Q pre-scaled by HD^-0.5 * log2(e); softmax in exp2 domain with defer-max (THR=8).
#define SQ 2048

__global__ __launch_bounds__(256, 2) void attn_kernel(const u16* __restrict__ Q,
                                                      const u16* __restrict__ KV,
                                                      float* __restrict__ O) {
  __shared__ u16 Ks[2 * 64 * 64];  // [buf][j][d], 16B-block bk holds dblk = bk ^ (j&7)
  __shared__ u16 Vt[2 * 64 * 64];  // [buf][d][j], byte = d*128 + ((j*2) ^ (((d^(d>>3))&7)<<4))

  int qt = blockIdx.x & 15;
  int bh = blockIdx.x >> 4;
  int b = bh >> 4, h = bh & 15;
  int tid = threadIdx.x;
  int w = tid >> 6, l = tid & 63;
  int li = l & 31, hi = l >> 5;
  int jr = l >> 3, bk = l & 7;   // K-staging coords

  const u16* kbase = KV + (size_t)b * SQ * 2048 + (size_t)h * 64;
  const u16* vbase = kbase + 1024;
  int i0g = qt * 128 + w * 32;
  const u16* qrow = Q + (size_t)(b * SQ + i0g + li) * 1024 + h * 64;

  bf16x8 qf0 = *(const bf16x8*)(qrow + 0  + hi * 8);
  bf16x8 qf1 = *(const bf16x8*)(qrow + 16 + hi * 8);
  bf16x8 qf2 = *(const bf16x8*)(qrow + 32 + hi * 8);
  bf16x8 qf3 = *(const bf16x8*)(qrow + 48 + hi * 8);

  // prologue: stage tile 0
  {
    const u16* gk0 = kbase + (size_t)(w * 8 + jr) * 2048 + ((bk ^ jr) * 8);
    __builtin_amdgcn_global_load_lds(AS1(gk0), AS3(Ks + w * 512), 16, 0, 0);
    const u16* gk1 = kbase + (size_t)(32 + w * 8 + jr) * 2048 + ((bk ^ jr) * 8);
    __builtin_amdgcn_global_load_lds(AS1(gk1), AS3(Ks + 2048 + w * 512), 16, 0, 0);
  }
  uint4 vregA = *(const uint4*)(vbase + (size_t)(tid >> 3) * 2048 + (tid & 7) * 8);
  uint4 vregB = *(const uint4*)(vbase + (size_t)(32 + (tid >> 3)) * 2048 + (tid & 7) * 8);

  float m_run = -1e30f, l_run = 0.f;
  f32x16 acc0, acc1;
#pragma unroll
  for (int r = 0; r < 16; ++r) { acc0[r] = 0.f; acc1[r] = 0.f; }

  for (int t = 0; t < SQ / 64; ++t) {
    int cur = t & 1;
    u16* Ksc = Ks + cur * 4096;
    u16* Vtc = Vt + cur * 4096;
    __syncthreads();               // K[cur] landed (vmcnt drain), prev compute done
    // V transpose-store, both 32-j halves (bank block e^a varies per e: 2-way max)
    {
      int a = tid & 7, jj0 = tid >> 3;
      const u16* pa_ = (const u16*)&vregA;
#pragma unroll
      for (int e = 0; e < 8; ++e)
        *(u16*)((char*)Vtc + (a * 8 + e) * 128 + ((jj0 * 2) ^ ((e ^ a) << 4))) = pa_[e];
      const u16* pb_ = (const u16*)&vregB;
      int jj1 = 32 + jj0;
#pragma unroll
      for (int e = 0; e < 8; ++e)
        *(u16*)((char*)Vtc + (a * 8 + e) * 128 + ((jj1 * 2) ^ ((e ^ a) << 4))) = pb_[e];
    }
    __syncthreads();               // Vt visible
    if (t + 1 < SQ / 64) {         // prefetch next tile, stays in flight across compute
      int nxt = cur ^ 1;
      int j0n = (t + 1) * 64;
      const u16* gk0 = kbase + (size_t)(j0n + w * 8 + jr) * 2048 + ((bk ^ jr) * 8);
      __builtin_amdgcn_global_load_lds(AS1(gk0), AS3(Ks + nxt * 4096 + w * 512), 16, 0, 0);
      const u16* gk1 = kbase + (size_t)(j0n + 32 + w * 8 + jr) * 2048 + ((bk ^ jr) * 8);
      __builtin_amdgcn_global_load_lds(AS1(gk1), AS3(Ks + nxt * 4096 + 2048 + w * 512), 16, 0, 0);
      vregA = *(const uint4*)(vbase + (size_t)(j0n + (tid >> 3)) * 2048 + (tid & 7) * 8);
      vregB = *(const uint4*)(vbase + (size_t)(j0n + 32 + (tid >> 3)) * 2048 + (tid & 7) * 8);
    }
    // ---- swapped QK^T (S^T: lane's col = its own q-row li)
    f32x16 s0, s1;
#pragma unroll
    for (int r = 0; r < 16; ++r) { s0[r] = 0.f; s1[r] = 0.f; }
    int swk = (li & 7) << 4;
    __builtin_amdgcn_s_setprio(1);
#pragma unroll
    for (int kb = 0; kb < 4; ++kb) {
      bf16x8 k0 = *(const bf16x8*)((const char*)Ksc + li * 128        + ((kb * 32 + hi * 16) ^ swk));
      bf16x8 k1 = *(const bf16x8*)((const char*)Ksc + (32 + li) * 128 + ((kb * 32 + hi * 16) ^ swk));
      bf16x8 qq = (kb == 0) ? qf0 : (kb == 1) ? qf1 : (kb == 2) ? qf2 : qf3;
      s0 = __builtin_amdgcn_mfma_f32_32x32x16_bf16(k0, qq, s0, 0, 0, 0);
      s1 = __builtin_amdgcn_mfma_f32_32x32x16_bf16(k1, qq, s1, 0, 0, 0);
    }
    __builtin_amdgcn_s_setprio(0);
    // ---- online softmax (log2 domain), lane-local row, defer-max THR=8
    float pm = fmaxf(s0[0], s0[1]);
#pragma unroll
    for (int r = 2; r < 16; r += 2) pm = fmaxf(fmaxf(pm, s0[r]), s0[r + 1]);
#pragma unroll
    for (int r = 0; r < 16; r += 2) pm = fmaxf(fmaxf(pm, s1[r]), s1[r + 1]);
    pm = fmaxf(pm, __shfl_xor(pm, 32));
    if (!__all(pm <= m_run + 8.0f)) {
      float mnew = fmaxf(m_run, pm);
      float esc = exp2_fast(m_run - mnew);
      m_run = mnew;
      l_run *= esc;
#pragma unroll
      for (int r = 0; r < 16; ++r) { acc0[r] *= esc; acc1[r] *= esc; }
    }
    float p0[16], p1[16];
    float sum = 0.f;
#pragma unroll
    for (int r = 0; r < 16; ++r) { p0[r] = exp2_fast(s0[r] - m_run); sum += p0[r]; }
#pragma unroll
    for (int r = 0; r < 16; ++r) { p1[r] = exp2_fast(s1[r] - m_run); sum += p1[r]; }
    sum += __shfl_xor(sum, 32);
    l_run += sum;
    // ---- pack P -> bf16 A-frag layout (cvt_pk + permlane32_swap)
    unsigned pw[16];
#pragma unroll
    for (int i2 = 0; i2 < 8; ++i2) {
      asm("v_cvt_pk_bf16_f32 %0, %1, %2" : "=v"(pw[i2])     : "v"(p0[2 * i2]), "v"(p0[2 * i2 + 1]));
      asm("v_cvt_pk_bf16_f32 %0, %1, %2" : "=v"(pw[8 + i2]) : "v"(p1[2 * i2]), "v"(p1[2 * i2 + 1]));
    }
#pragma unroll
    for (int gB = 0; gB < 2; ++gB) {
      int o = gB * 8;
      asm volatile("v_permlane32_swap_b32 %0, %1" : "+v"(pw[o + 0]), "+v"(pw[o + 2]));
      asm volatile("v_permlane32_swap_b32 %0, %1" : "+v"(pw[o + 1]), "+v"(pw[o + 3]));
      asm volatile("v_permlane32_swap_b32 %0, %1" : "+v"(pw[o + 4]), "+v"(pw[o + 6]));
      asm volatile("v_permlane32_swap_b32 %0, %1" : "+v"(pw[o + 5]), "+v"(pw[o + 7]));
    }
    // ---- PV as O^T: acc[db] += mfma(Vt rows d, P rows i)
    __builtin_amdgcn_s_setprio(1);
#pragma unroll
    for (int kb2 = 0; kb2 < 4; ++kb2) {
      uint4 ufr;
      ufr.x = pw[kb2 * 4 + 0]; ufr.y = pw[kb2 * 4 + 1];
      ufr.z = pw[kb2 * 4 + 2]; ufr.w = pw[kb2 * 4 + 3];
      bf16x8 pa = *(bf16x8*)&ufr;
      int jbyte = kb2 * 32 + hi * 16;
      int d0_ = li, d1_ = 32 + li;
      bf16x8 v0 = *(const bf16x8*)((const char*)Vtc + d0_ * 128 + (jbyte ^ (((d0_ ^ (d0_ >> 3)) & 7) << 4)));
      bf16x8 v1 = *(const bf16x8*)((const char*)Vtc + d1_ * 128 + (jbyte ^ (((d1_ ^ (d1_ >> 3)) & 7) << 4)));
      acc0 = __builtin_amdgcn_mfma_f32_32x32x16_bf16(v0, pa, acc0, 0, 0, 0);
      acc1 = __builtin_amdgcn_mfma_f32_32x32x16_bf16(v1, pa, acc1, 0, 0, 0);
    }
    __builtin_amdgcn_s_setprio(0);
  }
  // ---- epilogue
  float inv = 1.f / l_run;
  float* orow = O + ((size_t)(b * SQ + i0g + li) * 1024 + h * 64);
#pragma unroll
  for (int g = 0; g < 4; ++g) {
    f32x4 o0, o1;
#pragma unroll
    for (int q_ = 0; q_ < 4; ++q_) {
      o0[q_] = acc0[g * 4 + q_] * inv;
      o1[q_] = acc1[g * 4 + q_] * inv;
    }
    *(f32x4*)(orow + 8 * g + 4 * hi) = o0;
    *(f32x4*)(orow + 32 + 8 * g + 4 * hi) = o1;
  }
}

extern "C" void kernel_launch(void* const* d_in, const int* in_sizes, int n_in,
                              void* d_out, int out_size, void* d_ws, size_t ws_size,
                              hipStream_t stream) {
  (void)in_sizes; (void)n_in; (void)out_size; (void)ws_size;
  const float* x   = (const float*)d_in[0];
  const float* ctx = (const float*)d_in[1];
  const float* Wq  = (const float*)d_in[2];
  const float* Wkv = (const float*)d_in[3];
  float* out = (float*)d_out;
  char* ws = (char*)d_ws;

  u16* xb  = (u16*)(ws);                       // x bf16   [4096][1024]  8 MB
  u16* cb  = (u16*)(ws + (8ull  << 20));       // ctx bf16 [4096][1024]  8 MB
  u16* wqb = (u16*)(ws + (16ull << 20));       // Wq bf16  [1024][1024]  2 MB
  u16* wkb = (u16*)(ws + (18ull << 20));       // Wkv bf16 [2048][1024]  4 MB
  u16* q   = (u16*)(ws + (22ull << 20));       // q bf16, pre-scaled by 0.125*log2(e)
  u16* kv  = (u16*)(ws + (30ull << 20));       // kv bf16  [4096][2048] 16 MB

  auto cast = [&](const float* src, u16* dst, int n) {
    int n4 = n >> 2;
    int blocks = (n4 + 255) / 256;
    if (blocks > 2048) blocks = 2048;
    cast_f32_bf16<<<blocks, 256, 0, stream>>>((const float4*)src, (ushort4*)dst, n4);
  };
  cast(x,   xb,  4096 * 1024);
  cast(ctx, cb,  4096 * 1024);
  cast(Wq,  wqb, 1024 * 1024);
  cast(Wkv, wkb, 2048 * 1024);

  // q = (0.125*log2e) * x . Wq^T  — softmax runs in exp2 domain
  gemm_nt_bf16<<<32 * 8, 256, 0, stream>>>(xb, wqb, q, 4096, 1024, 1024, 0.125f * 1.44269504f);
  gemm_nt_bf16<<<32 * 16, 256, 0, stream>>>(cb, wkb, kv, 4096, 2048, 1024, 1.0f);

  attn_kernel<<<512, 256, 0, stream>>>(q, kv, out);
}

// Round 4
// 114.143 us; speedup vs baseline: 2.0621x; 1.1706x over previous
//
#include <hip/hip_runtime.h>
#include <hip/hip_bf16.h>
#include <stdint.h>

typedef unsigned short u16;
typedef __attribute__((ext_vector_type(8))) __bf16 bf16x8;
typedef __attribute__((ext_vector_type(4))) float f32x4;
typedef __attribute__((ext_vector_type(16))) float f32x16;

#define AS1(p) ((const __attribute__((address_space(1))) void*)(p))
#define AS3(p) ((__attribute__((address_space(3))) void*)(p))

__device__ __forceinline__ u16 f2bf(float f) {
  union { float f; uint32_t u; } c; c.f = f;
  uint32_t u = c.u;
  u += 0x7fffu + ((u >> 16) & 1u);   // RTNE
  return (u16)(u >> 16);
}

__device__ __forceinline__ float exp2_fast(float x) {
  float r; asm("v_exp_f32 %0, %1" : "=v"(r) : "v"(x)); return r;
}

// ---------------- fused cast fp32 -> bf16: 4 streams, one launch ----------------
// blocks 0..511 -> x, 512..1023 -> ctx, 1024..1151 -> Wq, 1152..1407 -> Wkv
__global__ __launch_bounds__(256) void cast4_f32_bf16(
    const float4* __restrict__ s0, ushort4* __restrict__ d0, int n0,
    const float4* __restrict__ s1, ushort4* __restrict__ d1, int n1,
    const float4* __restrict__ s2, ushort4* __restrict__ d2, int n2,
    const float4* __restrict__ s3, ushort4* __restrict__ d3, int n3) {
  int bid = blockIdx.x;
  const float4* src; ushort4* dst; int n4, b0, nb;
  if (bid < 512)       { src = s0; dst = d0; n4 = n0; b0 = 0;    nb = 512; }
  else if (bid < 1024) { src = s1; dst = d1; n4 = n1; b0 = 512;  nb = 512; }
  else if (bid < 1152) { src = s2; dst = d2; n4 = n2; b0 = 1024; nb = 128; }
  else                 { src = s3; dst = d3; n4 = n3; b0 = 1152; nb = 256; }
  int stride = nb * 256;
  for (int i = (bid - b0) * 256 + threadIdx.x; i < n4; i += stride) {
    float4 v = src[i];
    ushort4 o;
    o.x = f2bf(v.x); o.y = f2bf(v.y); o.z = f2bf(v.z); o.w = f2bf(v.w);
    dst[i] = o;
  }
}

// ---------------- fused NT GEMM (q + kv), double-buffered, counted vmcnt ----------------
// grid = 768 blocks x 256 thr (3 blocks/CU). Blocks 0..255: q = scale_q * xb.Wq^T
// (M=4096,N=1024). Blocks 256..767: kv = cb.Wkv^T (M=4096,N=2048). K=1024, BK=32.
__global__ __launch_bounds__(256) void gemm_fused(const u16* __restrict__ xb,
                                                  const u16* __restrict__ wqb,
                                                  u16* __restrict__ qo,
                                                  const u16* __restrict__ cb,
                                                  const u16* __restrict__ wkb,
                                                  u16* __restrict__ kvo,
                                                  float scale_q) {
  __shared__ u16 As[2][128 * 32];
  __shared__ u16 Bs[2][128 * 32];
  const int K = 1024;
  int bid = blockIdx.x;
  const u16 *A, *B; u16* C; int N, bm, bn; float scale;
  if (bid < 256) { A = xb; B = wqb; C = qo;  N = 1024; bm = bid >> 3; bn = bid & 7;  scale = scale_q; }
  else { int b2 = bid - 256; A = cb; B = wkb; C = kvo; N = 2048; bm = b2 >> 4; bn = b2 & 15; scale = 1.0f; }

  int tid = threadIdx.x;
  int w = tid >> 6, l = tid & 63;
  int wr = w >> 1, wc = w & 1;
  int lr = l & 15, lg = l >> 4;

  const u16* Abase = A + (size_t)(bm * 128 + (l >> 2)) * K + (l & 3) * 8;
  const u16* Bbase = B + (size_t)(bn * 128 + (l >> 2)) * K + (l & 3) * 8;

  f32x4 acc[4][4];
#pragma unroll
  for (int i = 0; i < 4; ++i)
#pragma unroll
    for (int j = 0; j < 4; ++j) acc[i][j] = (f32x4){0.f, 0.f, 0.f, 0.f};

  // STAGE(buf, k0): 4 gload_lds per thread (vmcnt += 4 per wave)
#define STAGE(buf, k0)                                                              \
  {                                                                                 \
    _Pragma("unroll")                                                               \
    for (int t2 = 0; t2 < 2; ++t2) {                                                \
      int seg = w * 2 + t2;                                                         \
      __builtin_amdgcn_global_load_lds(AS1(Abase + (size_t)seg * 16 * K + (k0)),    \
                                       AS3(&As[buf][seg * 512]), 16, 0, 0);         \
      __builtin_amdgcn_global_load_lds(AS1(Bbase + (size_t)seg * 16 * K + (k0)),    \
                                       AS3(&Bs[buf][seg * 512]), 16, 0, 0);         \
    }                                                                               \
  }

  STAGE(0, 0);
  for (int t = 0; t < 32; ++t) {
    int cur = t & 1;
    if (t < 31) {
      STAGE(cur ^ 1, (t + 1) * 32);
      asm volatile("s_waitcnt vmcnt(4)" ::: "memory");   // cur's 4 loads landed; next 4 in flight
    } else {
      asm volatile("s_waitcnt vmcnt(0)" ::: "memory");
    }
    __builtin_amdgcn_s_barrier();                        // all waves' cur-tile LDS writes visible
    bf16x8 af[4], bb[4];
#pragma unroll
    for (int i = 0; i < 4; ++i)
      af[i] = *(const bf16x8*)(&As[cur][(wr * 64 + i * 16 + lr) * 32 + lg * 8]);
#pragma unroll
    for (int j = 0; j < 4; ++j)
      bb[j] = *(const bf16x8*)(&Bs[cur][(wc * 64 + j * 16 + lr) * 32 + lg * 8]);
    asm volatile("s_waitcnt lgkmcnt(0)" ::: "memory");
    __builtin_amdgcn_sched_barrier(0);                   // rule 18: don't hoist MFMA above the wait
#pragma unroll
    for (int i = 0; i < 4; ++i)
#pragma unroll
      for (int j = 0; j < 4; ++j)
        acc[i][j] = __builtin_amdgcn_mfma_f32_16x16x32_bf16(af[i], bb[j], acc[i][j], 0, 0, 0);
    __builtin_amdgcn_s_barrier();                        // reads done before buf reuse next iter
  }
#undef STAGE

#pragma unroll
  for (int i = 0; i < 4; ++i)
#pragma unroll
    for (int j = 0; j < 4; ++j)
#pragma unroll
      for (int r = 0; r < 4; ++r) {
        int row = bm * 128 + wr * 64 + i * 16 + lg * 4 + r;
        int col = bn * 128 + wc * 64 + j * 16 + lr;
        C[(size_t)row * N + col] = f2bf(acc[i][j][r] * scale);
      }
}

// ---------------- flash attention: 4 waves x 32 q-rows, 32x32 swapped QK^T ----------------
// grid = (S/128) * B * H = 512 blocks (2 blocks/CU), 256 threads.
// Q pre-scaled by HD^-0.5 * log2(e); softmax in exp2 domain with defer-max (THR=8).
#define SQ 2048

__global__ __launch_bounds__(256, 2) void attn_kernel(const u16* __restrict__ Q,
                                                      const u16* __restrict__ KV,
                                                      float* __restrict__ O) {
  __shared__ u16 Ks[2 * 64 * 64];  // [buf][j][d], 16B-block bk holds dblk = bk ^ (j&7)
  __shared__ u16 Vt[2 * 64 * 64];  // [buf][d][j], byte = d*128 + ((j*2) ^ (((d^(d>>3))&7)<<4))

  int qt = blockIdx.x & 15;
  int bh = blockIdx.x >> 4;
  int b = bh >> 4, h = bh & 15;
  int tid = threadIdx.x;
  int w = tid >> 6, l = tid & 63;
  int li = l & 31, hi = l >> 5;
  int jr = l >> 3, bk = l & 7;   // K-staging coords

  const u16* kbase = KV + (size_t)b * SQ * 2048 + (size_t)h * 64;
  const u16* vbase = kbase + 1024;
  int i0g = qt * 128 + w * 32;
  const u16* qrow = Q + (size_t)(b * SQ + i0g + li) * 1024 + h * 64;

  bf16x8 qf0 = *(const bf16x8*)(qrow + 0  + hi * 8);
  bf16x8 qf1 = *(const bf16x8*)(qrow + 16 + hi * 8);
  bf16x8 qf2 = *(const bf16x8*)(qrow + 32 + hi * 8);
  bf16x8 qf3 = *(const bf16x8*)(qrow + 48 + hi * 8);

  // prologue: stage tile 0
  {
    const u16* gk0 = kbase + (size_t)(w * 8 + jr) * 2048 + ((bk ^ jr) * 8);
    __builtin_amdgcn_global_load_lds(AS1(gk0), AS3(Ks + w * 512), 16, 0, 0);
    const u16* gk1 = kbase + (size_t)(32 + w * 8 + jr) * 2048 + ((bk ^ jr) * 8);
    __builtin_amdgcn_global_load_lds(AS1(gk1), AS3(Ks + 2048 + w * 512), 16, 0, 0);
  }
  uint4 vregA = *(const uint4*)(vbase + (size_t)(tid >> 3) * 2048 + (tid & 7) * 8);
  uint4 vregB = *(const uint4*)(vbase + (size_t)(32 + (tid >> 3)) * 2048 + (tid & 7) * 8);

  float m_run = -1e30f, l_run = 0.f;
  f32x16 acc0, acc1;
#pragma unroll
  for (int r = 0; r < 16; ++r) { acc0[r] = 0.f; acc1[r] = 0.f; }

  for (int t = 0; t < SQ / 64; ++t) {
    int cur = t & 1;
    u16* Ksc = Ks + cur * 4096;
    u16* Vtc = Vt + cur * 4096;
    __syncthreads();               // K[cur] landed (vmcnt drain), prev compute done
    // V transpose-store, both 32-j halves (bank block e^a varies per e: 2-way max)
    {
      int a = tid & 7, jj0 = tid >> 3;
      const u16* pa_ = (const u16*)&vregA;
#pragma unroll
      for (int e = 0; e < 8; ++e)
        *(u16*)((char*)Vtc + (a * 8 + e) * 128 + ((jj0 * 2) ^ ((e ^ a) << 4))) = pa_[e];
      const u16* pb_ = (const u16*)&vregB;
      int jj1 = 32 + jj0;
#pragma unroll
      for (int e = 0; e < 8; ++e)
        *(u16*)((char*)Vtc + (a * 8 + e) * 128 + ((jj1 * 2) ^ ((e ^ a) << 4))) = pb_[e];
    }
    __syncthreads();               // Vt visible
    if (t + 1 < SQ / 64) {         // prefetch next tile, stays in flight across compute
      int nxt = cur ^ 1;
      int j0n = (t + 1) * 64;
      const u16* gk0 = kbase + (size_t)(j0n + w * 8 + jr) * 2048 + ((bk ^ jr) * 8);
      __builtin_amdgcn_global_load_lds(AS1(gk0), AS3(Ks + nxt * 4096 + w * 512), 16, 0, 0);
      const u16* gk1 = kbase + (size_t)(j0n + 32 + w * 8 + jr) * 2048 + ((bk ^ jr) * 8);
      __builtin_amdgcn_global_load_lds(AS1(gk1), AS3(Ks + nxt * 4096 + 2048 + w * 512), 16, 0, 0);
      vregA = *(const uint4*)(vbase + (size_t)(j0n + (tid >> 3)) * 2048 + (tid & 7) * 8);
      vregB = *(const uint4*)(vbase + (size_t)(j0n + 32 + (tid >> 3)) * 2048 + (tid & 7) * 8);
    }
    // ---- swapped QK^T (S^T: lane's col = its own q-row li)
    f32x16 s0, s1;
#pragma unroll
    for (int r = 0; r < 16; ++r) { s0[r] = 0.f; s1[r] = 0.f; }
    int swk = (li & 7) << 4;
    __builtin_amdgcn_s_setprio(1);
#pragma unroll
    for (int kb = 0; kb < 4; ++kb) {
      bf16x8 k0 = *(const bf16x8*)((const char*)Ksc + li * 128        + ((kb * 32 + hi * 16) ^ swk));
      bf16x8 k1 = *(const bf16x8*)((const char*)Ksc + (32 + li) * 128 + ((kb * 32 + hi * 16) ^ swk));
      bf16x8 qq = (kb == 0) ? qf0 : (kb == 1) ? qf1 : (kb == 2) ? qf2 : qf3;
      s0 = __builtin_amdgcn_mfma_f32_32x32x16_bf16(k0, qq, s0, 0, 0, 0);
      s1 = __builtin_amdgcn_mfma_f32_32x32x16_bf16(k1, qq, s1, 0, 0, 0);
    }
    __builtin_amdgcn_s_setprio(0);
    // ---- online softmax (log2 domain), lane-local row, defer-max THR=8
    float pm = fmaxf(s0[0], s0[1]);
#pragma unroll
    for (int r = 2; r < 16; r += 2) pm = fmaxf(fmaxf(pm, s0[r]), s0[r + 1]);
#pragma unroll
    for (int r = 0; r < 16; r += 2) pm = fmaxf(fmaxf(pm, s1[r]), s1[r + 1]);
    pm = fmaxf(pm, __shfl_xor(pm, 32));
    if (!__all(pm <= m_run + 8.0f)) {
      float mnew = fmaxf(m_run, pm);
      float esc = exp2_fast(m_run - mnew);
      m_run = mnew;
      l_run *= esc;
#pragma unroll
      for (int r = 0; r < 16; ++r) { acc0[r] *= esc; acc1[r] *= esc; }
    }
    float p0[16], p1[16];
    float sum = 0.f;
#pragma unroll
    for (int r = 0; r < 16; ++r) { p0[r] = exp2_fast(s0[r] - m_run); sum += p0[r]; }
#pragma unroll
    for (int r = 0; r < 16; ++r) { p1[r] = exp2_fast(s1[r] - m_run); sum += p1[r]; }
    sum += __shfl_xor(sum, 32);
    l_run += sum;
    // ---- pack P -> bf16 A-frag layout (cvt_pk + permlane32_swap)
    unsigned pw[16];
#pragma unroll
    for (int i2 = 0; i2 < 8; ++i2) {
      asm("v_cvt_pk_bf16_f32 %0, %1, %2" : "=v"(pw[i2])     : "v"(p0[2 * i2]), "v"(p0[2 * i2 + 1]));
      asm("v_cvt_pk_bf16_f32 %0, %1, %2" : "=v"(pw[8 + i2]) : "v"(p1[2 * i2]), "v"(p1[2 * i2 + 1]));
    }
#pragma unroll
    for (int gB = 0; gB < 2; ++gB) {
      int o = gB * 8;
      asm volatile("v_permlane32_swap_b32 %0, %1" : "+v"(pw[o + 0]), "+v"(pw[o + 2]));
      asm volatile("v_permlane32_swap_b32 %0, %1" : "+v"(pw[o + 1]), "+v"(pw[o + 3]));
      asm volatile("v_permlane32_swap_b32 %0, %1" : "+v"(pw[o + 4]), "+v"(pw[o + 6]));
      asm volatile("v_permlane32_swap_b32 %0, %1" : "+v"(pw[o + 5]), "+v"(pw[o + 7]));
    }
    // ---- PV as O^T: acc[db] += mfma(Vt rows d, P rows i)
    __builtin_amdgcn_s_setprio(1);
#pragma unroll
    for (int kb2 = 0; kb2 < 4; ++kb2) {
      uint4 ufr;
      ufr.x = pw[kb2 * 4 + 0]; ufr.y = pw[kb2 * 4 + 1];
      ufr.z = pw[kb2 * 4 + 2]; ufr.w = pw[kb2 * 4 + 3];
      bf16x8 pa = *(bf16x8*)&ufr;
      int jbyte = kb2 * 32 + hi * 16;
      int d0_ = li, d1_ = 32 + li;
      bf16x8 v0 = *(const bf16x8*)((const char*)Vtc + d0_ * 128 + (jbyte ^ (((d0_ ^ (d0_ >> 3)) & 7) << 4)));
      bf16x8 v1 = *(const bf16x8*)((const char*)Vtc + d1_ * 128 + (jbyte ^ (((d1_ ^ (d1_ >> 3)) & 7) << 4)));
      acc0 = __builtin_amdgcn_mfma_f32_32x32x16_bf16(v0, pa, acc0, 0, 0, 0);
      acc1 = __builtin_amdgcn_mfma_f32_32x32x16_bf16(v1, pa, acc1, 0, 0, 0);
    }
    __builtin_amdgcn_s_setprio(0);
  }
  // ---- epilogue
  float inv = 1.f / l_run;
  float* orow = O + ((size_t)(b * SQ + i0g + li) * 1024 + h * 64);
#pragma unroll
  for (int g = 0; g < 4; ++g) {
    f32x4 o0, o1;
#pragma unroll
    for (int q_ = 0; q_ < 4; ++q_) {
      o0[q_] = acc0[g * 4 + q_] * inv;
      o1[q_] = acc1[g * 4 + q_] * inv;
    }
    *(f32x4*)(orow + 8 * g + 4 * hi) = o0;
    *(f32x4*)(orow + 32 + 8 * g + 4 * hi) = o1;
  }
}

extern "C" void kernel_launch(void* const* d_in, const int* in_sizes, int n_in,
                              void* d_out, int out_size, void* d_ws, size_t ws_size,
                              hipStream_t stream) {
  (void)in_sizes; (void)n_in; (void)out_size; (void)ws_size;
  const float* x   = (const float*)d_in[0];
  const float* ctx = (const float*)d_in[1];
  const float* Wq  = (const float*)d_in[2];
  const float* Wkv = (const float*)d_in[3];
  float* out = (float*)d_out;
  char* ws = (char*)d_ws;

  u16* xb  = (u16*)(ws);                       // x bf16   [4096][1024]  8 MB
  u16* cb  = (u16*)(ws + (8ull  << 20));       // ctx bf16 [4096][1024]  8 MB
  u16* wqb = (u16*)(ws + (16ull << 20));       // Wq bf16  [1024][1024]  2 MB
  u16* wkb = (u16*)(ws + (18ull << 20));       // Wkv bf16 [2048][1024]  4 MB
  u16* q   = (u16*)(ws + (22ull << 20));       // q bf16, pre-scaled by 0.125*log2(e)
  u16* kv  = (u16*)(ws + (30ull << 20));       // kv bf16  [4096][2048] 16 MB

  cast4_f32_bf16<<<1408, 256, 0, stream>>>(
      (const float4*)x,   (ushort4*)xb,  (4096 * 1024) / 4,
      (const float4*)ctx, (ushort4*)cb,  (4096 * 1024) / 4,
      (const float4*)Wq,  (ushort4*)wqb, (1024 * 1024) / 4,
      (const float4*)Wkv, (ushort4*)wkb, (2048 * 1024) / 4);

  // q = (0.125*log2e) * x.Wq^T ; kv = ctx.Wkv^T  — one fused launch, 768 blocks
  gemm_fused<<<768, 256, 0, stream>>>(xb, wqb, q, cb, wkb, kv, 0.125f * 1.44269504f);

  attn_kernel<<<512, 256, 0, stream>>>(q, kv, out);
}

// Round 5
// 110.902 us; speedup vs baseline: 2.1224x; 1.0292x over previous
//
#include <hip/hip_runtime.h>
#include <hip/hip_bf16.h>
#include <stdint.h>

typedef unsigned short u16;
typedef __attribute__((ext_vector_type(8))) __bf16 bf16x8;
typedef __attribute__((ext_vector_type(4))) float f32x4;
typedef __attribute__((ext_vector_type(16))) float f32x16;

#define AS1(p) ((const __attribute__((address_space(1))) void*)(p))
#define AS3(p) ((__attribute__((address_space(3))) void*)(p))

__device__ __forceinline__ u16 f2bf(float f) {
  union { float f; uint32_t u; } c; c.f = f;
  uint32_t u = c.u;
  u += 0x7fffu + ((u >> 16) & 1u);   // RTNE
  return (u16)(u >> 16);
}

__device__ __forceinline__ float exp2_fast(float x) {
  float r; asm("v_exp_f32 %0, %1" : "=v"(r) : "v"(x)); return r;
}

// ---------------- fused cast fp32 -> bf16: 4 streams, one launch ----------------
__global__ __launch_bounds__(256) void cast4_f32_bf16(
    const float4* __restrict__ s0, ushort4* __restrict__ d0, int n0,
    const float4* __restrict__ s1, ushort4* __restrict__ d1, int n1,
    const float4* __restrict__ s2, ushort4* __restrict__ d2, int n2,
    const float4* __restrict__ s3, ushort4* __restrict__ d3, int n3) {
  int bid = blockIdx.x;
  const float4* src; ushort4* dst; int n4, b0, nb;
  if (bid < 512)       { src = s0; dst = d0; n4 = n0; b0 = 0;    nb = 512; }
  else if (bid < 1024) { src = s1; dst = d1; n4 = n1; b0 = 512;  nb = 512; }
  else if (bid < 1152) { src = s2; dst = d2; n4 = n2; b0 = 1024; nb = 128; }
  else                 { src = s3; dst = d3; n4 = n3; b0 = 1152; nb = 256; }
  int stride = nb * 256;
  for (int i = (bid - b0) * 256 + threadIdx.x; i < n4; i += stride) {
    float4 v = src[i];
    ushort4 o;
    o.x = f2bf(v.x); o.y = f2bf(v.y); o.z = f2bf(v.z); o.w = f2bf(v.w);
    dst[i] = o;
  }
}

// ---------------- fused NT GEMM (q + kv), double-buffered, counted vmcnt ----------------
__global__ __launch_bounds__(256) void gemm_fused(const u16* __restrict__ xb,
                                                  const u16* __restrict__ wqb,
                                                  u16* __restrict__ qo,
                                                  const u16* __restrict__ cb,
                                                  const u16* __restrict__ wkb,
                                                  u16* __restrict__ kvo,
                                                  float scale_q) {
  __shared__ u16 As[2][128 * 32];
  __shared__ u16 Bs[2][128 * 32];
  const int K = 1024;
  int bid = blockIdx.x;
  const u16 *A, *B; u16* C; int N, bm, bn; float scale;
  if (bid < 256) { A = xb; B = wqb; C = qo;  N = 1024; bm = bid >> 3; bn = bid & 7;  scale = scale_q; }
  else { int b2 = bid - 256; A = cb; B = wkb; C = kvo; N = 2048; bm = b2 >> 4; bn = b2 & 15; scale = 1.0f; }

  int tid = threadIdx.x;
  int w = tid >> 6, l = tid & 63;
  int wr = w >> 1, wc = w & 1;
  int lr = l & 15, lg = l >> 4;

  const u16* Abase = A + (size_t)(bm * 128 + (l >> 2)) * K + (l & 3) * 8;
  const u16* Bbase = B + (size_t)(bn * 128 + (l >> 2)) * K + (l & 3) * 8;

  f32x4 acc[4][4];
#pragma unroll
  for (int i = 0; i < 4; ++i)
#pragma unroll
    for (int j = 0; j < 4; ++j) acc[i][j] = (f32x4){0.f, 0.f, 0.f, 0.f};

#define STAGE(buf, k0)                                                              \
  {                                                                                 \
    _Pragma("unroll")                                                               \
    for (int t2 = 0; t2 < 2; ++t2) {                                                \
      int seg = w * 2 + t2;                                                         \
      __builtin_amdgcn_global_load_lds(AS1(Abase + (size_t)seg * 16 * K + (k0)),    \
                                       AS3(&As[buf][seg * 512]), 16, 0, 0);         \
      __builtin_amdgcn_global_load_lds(AS1(Bbase + (size_t)seg * 16 * K + (k0)),    \
                                       AS3(&Bs[buf][seg * 512]), 16, 0, 0);         \
    }                                                                               \
  }

  STAGE(0, 0);
  for (int t = 0; t < 32; ++t) {
    int cur = t & 1;
    if (t < 31) {
      STAGE(cur ^ 1, (t + 1) * 32);
      asm volatile("s_waitcnt vmcnt(4)" ::: "memory");
    } else {
      asm volatile("s_waitcnt vmcnt(0)" ::: "memory");
    }
    __builtin_amdgcn_s_barrier();
    bf16x8 af[4], bb[4];
#pragma unroll
    for (int i = 0; i < 4; ++i)
      af[i] = *(const bf16x8*)(&As[cur][(wr * 64 + i * 16 + lr) * 32 + lg * 8]);
#pragma unroll
    for (int j = 0; j < 4; ++j)
      bb[j] = *(const bf16x8*)(&Bs[cur][(wc * 64 + j * 16 + lr) * 32 + lg * 8]);
    asm volatile("s_waitcnt lgkmcnt(0)" ::: "memory");
    __builtin_amdgcn_sched_barrier(0);
#pragma unroll
    for (int i = 0; i < 4; ++i)
#pragma unroll
      for (int j = 0; j < 4; ++j)
        acc[i][j] = __builtin_amdgcn_mfma_f32_16x16x32_bf16(af[i], bb[j], acc[i][j], 0, 0, 0);
    __builtin_amdgcn_s_barrier();
  }
#undef STAGE

#pragma unroll
  for (int i = 0; i < 4; ++i)
#pragma unroll
    for (int j = 0; j < 4; ++j)
#pragma unroll
      for (int r = 0; r < 4; ++r) {
        int row = bm * 128 + wr * 64 + i * 16 + lg * 4 + r;
        int col = bn * 128 + wc * 64 + j * 16 + lr;
        C[(size_t)row * N + col] = f2bf(acc[i][j][r] * scale);
      }
}

// ---------------- flash attention: T15 double-pipeline, 32x32 swapped QK^T ----------------
// grid = 512 blocks (2/CU), 256 thr (4 waves x 32 q-rows). One barrier per tile.
// Pipeline: QKT(t) issue -> softmax-finish(t-1)+PV(t-1) (independent VALU/MFMA hides
// QKT drain) -> max-reduce(t). Two-state s regs with explicit A/B naming.
#define SQ 2048
#define NT 32

__global__ __launch_bounds__(256, 2) void attn_kernel(const u16* __restrict__ Q,
                                                      const u16* __restrict__ KV,
                                                      float* __restrict__ O) {
  __shared__ u16 Ks[2 * 64 * 64];  // [buf][j][d], 16B-block bk holds dblk = bk ^ (j&7)
  __shared__ u16 Vt[2 * 64 * 64];  // [buf][d][j], byte = d*128 + ((j*2) ^ (((d^(d>>3))&7)<<4))

  int qt = blockIdx.x & 15;
  int bh = blockIdx.x >> 4;
  int b = bh >> 4, h = bh & 15;
  int tid = threadIdx.x;
  int w = tid >> 6, l = tid & 63;
  int li = l & 31, hi = l >> 5;
  int jr = l >> 3, bk = l & 7;

  const u16* kbase = KV + (size_t)b * SQ * 2048 + (size_t)h * 64;
  const u16* vbase = kbase + 1024;
  int i0g = qt * 128 + w * 32;
  const u16* qrow = Q + (size_t)(b * SQ + i0g + li) * 1024 + h * 64;

  bf16x8 qf0 = *(const bf16x8*)(qrow + 0  + hi * 8);
  bf16x8 qf1 = *(const bf16x8*)(qrow + 16 + hi * 8);
  bf16x8 qf2 = *(const bf16x8*)(qrow + 32 + hi * 8);
  bf16x8 qf3 = *(const bf16x8*)(qrow + 48 + hi * 8);

  // prologue: stage tile 0
  {
    const u16* gk0 = kbase + (size_t)(w * 8 + jr) * 2048 + ((bk ^ jr) * 8);
    __builtin_amdgcn_global_load_lds(AS1(gk0), AS3(Ks + w * 512), 16, 0, 0);
    const u16* gk1 = kbase + (size_t)(32 + w * 8 + jr) * 2048 + ((bk ^ jr) * 8);
    __builtin_amdgcn_global_load_lds(AS1(gk1), AS3(Ks + 2048 + w * 512), 16, 0, 0);
  }
  uint4 vregA = *(const uint4*)(vbase + (size_t)(tid >> 3) * 2048 + (tid & 7) * 8);
  uint4 vregB = *(const uint4*)(vbase + (size_t)(32 + (tid >> 3)) * 2048 + (tid & 7) * 8);

  float m_run = -1e30f, l_run = 0.f;
  f32x16 acc0, acc1;
#pragma unroll
  for (int r = 0; r < 16; ++r) { acc0[r] = 0.f; acc1[r] = 0.f; }

  // V-store current tile to Vt[t&1] (read at PV(t) next iteration, after next barrier),
  // then prefetch tile t+1 (K -> Ks[(t+1)&1] async; V -> regs).
  auto stage_pf = [&](int t) {
    u16* Vtc = Vt + (t & 1) * 4096;
    int a = tid & 7, jj0 = tid >> 3;
    const u16* pa_ = (const u16*)&vregA;
#pragma unroll
    for (int e = 0; e < 8; ++e)
      *(u16*)((char*)Vtc + (a * 8 + e) * 128 + ((jj0 * 2) ^ ((e ^ a) << 4))) = pa_[e];
    const u16* pb_ = (const u16*)&vregB;
    int jj1 = 32 + jj0;
#pragma unroll
    for (int e = 0; e < 8; ++e)
      *(u16*)((char*)Vtc + (a * 8 + e) * 128 + ((jj1 * 2) ^ ((e ^ a) << 4))) = pb_[e];
    if (t + 1 < NT) {
      int j0n = (t + 1) * 64;
      u16* Ksn = Ks + ((t + 1) & 1) * 4096;
      const u16* gk0 = kbase + (size_t)(j0n + w * 8 + jr) * 2048 + ((bk ^ jr) * 8);
      __builtin_amdgcn_global_load_lds(AS1(gk0), AS3(Ksn + w * 512), 16, 0, 0);
      const u16* gk1 = kbase + (size_t)(j0n + 32 + w * 8 + jr) * 2048 + ((bk ^ jr) * 8);
      __builtin_amdgcn_global_load_lds(AS1(gk1), AS3(Ksn + 2048 + w * 512), 16, 0, 0);
      vregA = *(const uint4*)(vbase + (size_t)(j0n + (tid >> 3)) * 2048 + (tid & 7) * 8);
      vregB = *(const uint4*)(vbase + (size_t)(j0n + 32 + (tid >> 3)) * 2048 + (tid & 7) * 8);
    }
  };

  auto qkt = [&](int t, f32x16& n0, f32x16& n1) {
    const u16* Ksc = Ks + (t & 1) * 4096;
#pragma unroll
    for (int r = 0; r < 16; ++r) { n0[r] = 0.f; n1[r] = 0.f; }
    int swk = (li & 7) << 4;
    __builtin_amdgcn_s_setprio(1);
#pragma unroll
    for (int kb = 0; kb < 4; ++kb) {
      bf16x8 k0 = *(const bf16x8*)((const char*)Ksc + li * 128        + ((kb * 32 + hi * 16) ^ swk));
      bf16x8 k1 = *(const bf16x8*)((const char*)Ksc + (32 + li) * 128 + ((kb * 32 + hi * 16) ^ swk));
      bf16x8 qq = (kb == 0) ? qf0 : (kb == 1) ? qf1 : (kb == 2) ? qf2 : qf3;
      n0 = __builtin_amdgcn_mfma_f32_32x32x16_bf16(k0, qq, n0, 0, 0, 0);
      n1 = __builtin_amdgcn_mfma_f32_32x32x16_bf16(k1, qq, n1, 0, 0, 0);
    }
    __builtin_amdgcn_s_setprio(0);
  };

  // softmax-finish of tile tp (exp, sum, pack) + PV(tp). Uses m_run fixed by maxred(tp).
  auto finish_pv = [&](int tp, const f32x16& sp0, const f32x16& sp1) {
    const u16* Vtp = Vt + (tp & 1) * 4096;
    float p0[16], p1[16];
    float sum = 0.f;
#pragma unroll
    for (int r = 0; r < 16; ++r) { p0[r] = exp2_fast(sp0[r] - m_run); sum += p0[r]; }
#pragma unroll
    for (int r = 0; r < 16; ++r) { p1[r] = exp2_fast(sp1[r] - m_run); sum += p1[r]; }
    sum += __shfl_xor(sum, 32);
    l_run += sum;
    unsigned pw[16];
#pragma unroll
    for (int i2 = 0; i2 < 8; ++i2) {
      asm("v_cvt_pk_bf16_f32 %0, %1, %2" : "=v"(pw[i2])     : "v"(p0[2 * i2]), "v"(p0[2 * i2 + 1]));
      asm("v_cvt_pk_bf16_f32 %0, %1, %2" : "=v"(pw[8 + i2]) : "v"(p1[2 * i2]), "v"(p1[2 * i2 + 1]));
    }
#pragma unroll
    for (int gB = 0; gB < 2; ++gB) {
      int o = gB * 8;
      asm volatile("v_permlane32_swap_b32 %0, %1" : "+v"(pw[o + 0]), "+v"(pw[o + 2]));
      asm volatile("v_permlane32_swap_b32 %0, %1" : "+v"(pw[o + 1]), "+v"(pw[o + 3]));
      asm volatile("v_permlane32_swap_b32 %0, %1" : "+v"(pw[o + 4]), "+v"(pw[o + 6]));
      asm volatile("v_permlane32_swap_b32 %0, %1" : "+v"(pw[o + 5]), "+v"(pw[o + 7]));
    }
    __builtin_amdgcn_s_setprio(1);
#pragma unroll
    for (int kb2 = 0; kb2 < 4; ++kb2) {
      uint4 ufr;
      ufr.x = pw[kb2 * 4 + 0]; ufr.y = pw[kb2 * 4 + 1];
      ufr.z = pw[kb2 * 4 + 2]; ufr.w = pw[kb2 * 4 + 3];
      bf16x8 pa = *(bf16x8*)&ufr;
      int jbyte = kb2 * 32 + hi * 16;
      int d0_ = li, d1_ = 32 + li;
      bf16x8 v0 = *(const bf16x8*)((const char*)Vtp + d0_ * 128 + (jbyte ^ (((d0_ ^ (d0_ >> 3)) & 7) << 4)));
      bf16x8 v1 = *(const bf16x8*)((const char*)Vtp + d1_ * 128 + (jbyte ^ (((d1_ ^ (d1_ >> 3)) & 7) << 4)));
      acc0 = __builtin_amdgcn_mfma_f32_32x32x16_bf16(v0, pa, acc0, 0, 0, 0);
      acc1 = __builtin_amdgcn_mfma_f32_32x32x16_bf16(v1, pa, acc1, 0, 0, 0);
    }
    __builtin_amdgcn_s_setprio(0);
  };

  auto maxred = [&](const f32x16& n0, const f32x16& n1) {
    float pm = fmaxf(n0[0], n0[1]);
#pragma unroll
    for (int r = 2; r < 16; r += 2) pm = fmaxf(fmaxf(pm, n0[r]), n0[r + 1]);
#pragma unroll
    for (int r = 0; r < 16; r += 2) pm = fmaxf(fmaxf(pm, n1[r]), n1[r + 1]);
    pm = fmaxf(pm, __shfl_xor(pm, 32));
    if (!__all(pm <= m_run + 8.0f)) {
      float mnew = fmaxf(m_run, pm);
      float esc = exp2_fast(m_run - mnew);
      m_run = mnew;
      l_run *= esc;
#pragma unroll
      for (int r = 0; r < 16; ++r) { acc0[r] *= esc; acc1[r] *= esc; }
    }
  };

  f32x16 sa0, sa1, sb0, sb1;
  // ---- peel t=0
  __syncthreads();                 // K(0) landed
  stage_pf(0);
  qkt(0, sa0, sa1);
  maxred(sa0, sa1);
  // ---- main: pairs (t, t+1), t = 1,3,...,29
  for (int t = 1; t < NT - 1; t += 2) {
    __syncthreads();               // K(t) landed; Vt[(t-1)&1] visible; all waves past qkt(t-1)
    stage_pf(t);
    qkt(t, sb0, sb1);
    finish_pv(t - 1, sa0, sa1);
    maxred(sb0, sb1);
    __syncthreads();
    stage_pf(t + 1);
    qkt(t + 1, sa0, sa1);
    finish_pv(t, sb0, sb1);
    maxred(sa0, sa1);
  }
  // ---- tail t = NT-1 (odd)
  __syncthreads();
  stage_pf(NT - 1);
  qkt(NT - 1, sb0, sb1);
  finish_pv(NT - 2, sa0, sa1);
  maxred(sb0, sb1);
  // ---- epilogue: finish last tile (barrier for V-store(NT-1) visibility)
  __syncthreads();
  finish_pv(NT - 1, sb0, sb1);

  float inv = 1.f / l_run;
  float* orow = O + ((size_t)(b * SQ + i0g + li) * 1024 + h * 64);
#pragma unroll
  for (int g = 0; g < 4; ++g) {
    f32x4 o0, o1;
#pragma unroll
    for (int q_ = 0; q_ < 4; ++q_) {
      o0[q_] = acc0[g * 4 + q_] * inv;
      o1[q_] = acc1[g * 4 + q_] * inv;
    }
    *(f32x4*)(orow + 8 * g + 4 * hi) = o0;
    *(f32x4*)(orow + 32 + 8 * g + 4 * hi) = o1;
  }
}

extern "C" void kernel_launch(void* const* d_in, const int* in_sizes, int n_in,
                              void* d_out, int out_size, void* d_ws, size_t ws_size,
                              hipStream_t stream) {
  (void)in_sizes; (void)n_in; (void)out_size; (void)ws_size;
  const float* x   = (const float*)d_in[0];
  const float* ctx = (const float*)d_in[1];
  const float* Wq  = (const float*)d_in[2];
  const float* Wkv = (const float*)d_in[3];
  float* out = (float*)d_out;
  char* ws = (char*)d_ws;

  u16* xb  = (u16*)(ws);                       // x bf16   [4096][1024]  8 MB
  u16* cb  = (u16*)(ws + (8ull  << 20));       // ctx bf16 [4096][1024]  8 MB
  u16* wqb = (u16*)(ws + (16ull << 20));       // Wq bf16  [1024][1024]  2 MB
  u16* wkb = (u16*)(ws + (18ull << 20));       // Wkv bf16 [2048][1024]  4 MB
  u16* q   = (u16*)(ws + (22ull << 20));       // q bf16, pre-scaled by 0.125*log2(e)
  u16* kv  = (u16*)(ws + (30ull << 20));       // kv bf16  [4096][2048] 16 MB

  cast4_f32_bf16<<<1408, 256, 0, stream>>>(
      (const float4*)x,   (ushort4*)xb,  (4096 * 1024) / 4,
      (const float4*)ctx, (ushort4*)cb,  (4096 * 1024) / 4,
      (const float4*)Wq,  (ushort4*)wqb, (1024 * 1024) / 4,
      (const float4*)Wkv, (ushort4*)wkb, (2048 * 1024) / 4);

  gemm_fused<<<768, 256, 0, stream>>>(xb, wqb, q, cb, wkb, kv, 0.125f * 1.44269504f);

  attn_kernel<<<512, 256, 0, stream>>>(q, kv, out);
}